// Round 2
// baseline (849.152 us; speedup 1.0000x reference)
//
#include <hip/hip_runtime.h>
#include <cmath>

typedef __attribute__((ext_vector_type(8))) short bf16x8;
typedef __attribute__((ext_vector_type(4))) float f32x4;

#define TBLSZ (1 << 18)
#define TMASK (TBLSZ - 1)

struct ResArgs { float r[16]; };

__device__ __forceinline__ unsigned short f2bf(float f) {
    unsigned u = __float_as_uint(f);
    u += 0x7fffu + ((u >> 16) & 1u);   // RTNE
    return (unsigned short)(u >> 16);
}

__global__ __launch_bounds__(256) void hashgrid_mlp(
    const float* __restrict__ ipos,
    const float4* __restrict__ tables,   // [16][TBLSZ] float4
    const float* __restrict__ W1, const float* __restrict__ b1,
    const float* __restrict__ W2, const float* __restrict__ b2,
    const float* __restrict__ W3, const float* __restrict__ b3,
    float* __restrict__ out, ResArgs ra)
{
    // weights as bf16, row-major [out][k]
    __shared__ __attribute__((aligned(16))) unsigned short w1b[64 * 64];
    __shared__ __attribute__((aligned(16))) unsigned short w2b[64 * 64];
    __shared__ __attribute__((aligned(16))) unsigned short w3b[16 * 64]; // rows 8..15 zero
    __shared__ float bb[136];                                            // b1|b2|b3
    // activation blocks in MFMA B-frag layout:
    // [wave][blk = n*2 + kblk][lane][8 bf16] ; X[i][k] at blk=(iloc>>4)*2+(k>>5),
    // lane=(iloc&15)+16*((k&31)>>3), elem=k&7
    __shared__ __attribute__((aligned(16))) unsigned short xb[4][8][64][8];

    const int t = threadIdx.x;

    // ---- stage weights/biases into LDS (f32 -> bf16) ----
    {
        const int base = t * 16;
        #pragma unroll
        for (int e = 0; e < 16; e += 4) {
            float4 v = *(const float4*)(W1 + base + e);
            w1b[base + e + 0] = f2bf(v.x); w1b[base + e + 1] = f2bf(v.y);
            w1b[base + e + 2] = f2bf(v.z); w1b[base + e + 3] = f2bf(v.w);
        }
        #pragma unroll
        for (int e = 0; e < 16; e += 4) {
            float4 v = *(const float4*)(W2 + base + e);
            w2b[base + e + 0] = f2bf(v.x); w2b[base + e + 1] = f2bf(v.y);
            w2b[base + e + 2] = f2bf(v.z); w2b[base + e + 3] = f2bf(v.w);
        }
        if (t < 32) {                      // real W3 rows 0..7
            #pragma unroll
            for (int e = 0; e < 16; e += 4) {
                float4 v = *(const float4*)(W3 + base + e);
                w3b[base + e + 0] = f2bf(v.x); w3b[base + e + 1] = f2bf(v.y);
                w3b[base + e + 2] = f2bf(v.z); w3b[base + e + 3] = f2bf(v.w);
            }
        } else if (t < 64) {               // zero-pad rows 8..15
            const int zb = 512 + (t - 32) * 16;
            #pragma unroll
            for (int e = 0; e < 16; ++e) w3b[zb + e] = 0;
        }
        if (t < 64)        bb[t] = b1[t];
        else if (t < 128)  bb[t] = b2[t - 64];
        else if (t < 136)  bb[t] = b3[t - 128];
    }
    __syncthreads();

    const int w   = t >> 6;
    const int l   = t & 63;
    const int q   = l >> 4;
    const int l16 = l & 15;

    // ---- phase 1: hash-grid encode (one point per thread) ----
    {
        const long long gi = (long long)blockIdx.x * 256 + t;
        const float px = ipos[gi * 3 + 0];
        const float py = ipos[gi * 3 + 1];
        const float pz = ipos[gi * 3 + 2];
        const int n2base = ((t >> 4) & 3) * 2;

        #pragma unroll 2
        for (int lvl = 0; lvl < 16; ++lvl) {
            const float res = ra.r[lvl];
            float xl = px * res, yl = py * res, zl = pz * res;
            float fx = floorf(xl), fy = floorf(yl), fz = floorf(zl);
            float tx = xl - fx, ty = yl - fy, tz = zl - fz;
            unsigned cx = (unsigned)(int)fx, cy = (unsigned)(int)fy, cz = (unsigned)(int)fz;
            unsigned hx[2] = { cx, cx + 1u };
            unsigned hy[2] = { cy * 2654435761u, cy * 2654435761u + 2654435761u };
            unsigned hz[2] = { cz * 805459861u,  cz * 805459861u + 805459861u };
            float wx[2] = { 1.f - tx, tx }, wy[2] = { 1.f - ty, ty }, wz[2] = { 1.f - tz, tz };
            const float4* tbl = tables + (size_t)lvl * TBLSZ;
            float a0 = 0.f, a1 = 0.f, a2 = 0.f, a3 = 0.f;
            #pragma unroll
            for (int c = 0; c < 8; ++c) {
                const int ox = (c >> 2) & 1, oy = (c >> 1) & 1, oz = c & 1;
                unsigned h = (hx[ox] ^ hy[oy] ^ hz[oz]) & TMASK;
                float4 v = tbl[h];
                float ww = wx[ox] * wy[oy] * wz[oz];
                a0 = fmaf(ww, v.x, a0); a1 = fmaf(ww, v.y, a1);
                a2 = fmaf(ww, v.z, a2); a3 = fmaf(ww, v.w, a3);
            }
            // deposit feats (k = 4*lvl .. 4*lvl+3) into B-frag layout
            const int blk = n2base + (lvl >> 3);
            const int lp  = (t & 15) + 16 * ((lvl & 7) >> 1);
            uint2 pk;
            pk.x = (unsigned)f2bf(a0) | ((unsigned)f2bf(a1) << 16);
            pk.y = (unsigned)f2bf(a2) | ((unsigned)f2bf(a3) << 16);
            *(uint2*)&xb[w][blk][lp][(lvl & 1) * 4] = pk;
        }
    }
    // no barrier needed: each wave reads only its own xb[w] blocks (DS in-order per wave)

    // ---- phase 2: MLP via MFMA, transposed (D = W * X^T) ----
    for (int layer = 0; layer < 2; ++layer) {
        const unsigned short* wb = layer ? w2b : w1b;
        const int bof = layer * 64;
        f32x4 acc[4][4];
        #pragma unroll
        for (int m = 0; m < 4; ++m) {
            // A-frag: lane l -> row m*16+l16, k = kblk*32 + q*8 + r
            bf16x8 af0 = *(const bf16x8*)(wb + (m * 16 + l16) * 64 +  0 + q * 8);
            bf16x8 af1 = *(const bf16x8*)(wb + (m * 16 + l16) * 64 + 32 + q * 8);
            #pragma unroll
            for (int n = 0; n < 4; ++n) {
                f32x4 d = { 0.f, 0.f, 0.f, 0.f };
                d = __builtin_amdgcn_mfma_f32_16x16x32_bf16(af0, *(const bf16x8*)&xb[w][n * 2 + 0][l][0], d, 0, 0, 0);
                d = __builtin_amdgcn_mfma_f32_16x16x32_bf16(af1, *(const bf16x8*)&xb[w][n * 2 + 1][l][0], d, 0, 0, 0);
                acc[m][n] = d;
            }
        }
        // bias + relu, deposit h back into xb as next layer's B-frags
        // D layout: lane l, reg r -> h^T[j = m*16 + q*4 + r][i = n*16 + l16]
        #pragma unroll
        for (int m = 0; m < 4; ++m) {
            #pragma unroll
            for (int n = 0; n < 4; ++n) {
                #pragma unroll
                for (int rr = 0; rr < 4; rr += 2) {
                    const int j0 = m * 16 + q * 4 + rr;
                    float v0 = fmaxf(acc[m][n][rr]     + bb[bof + j0],     0.f);
                    float v1 = fmaxf(acc[m][n][rr + 1] + bb[bof + j0 + 1], 0.f);
                    unsigned pk = (unsigned)f2bf(v0) | ((unsigned)f2bf(v1) << 16);
                    const int blk = n * 2 + (j0 >> 5);
                    const int lp  = l16 + 16 * ((j0 & 31) >> 3);
                    *(unsigned*)&xb[w][blk][lp][j0 & 7] = pk;
                }
            }
        }
    }

    // ---- layer 3: [8x64] (padded to 16) + bias + sigmoid, coalesced store ----
    {
        bf16x8 af0 = *(const bf16x8*)(w3b + l16 * 64 +  0 + q * 8);
        bf16x8 af1 = *(const bf16x8*)(w3b + l16 * 64 + 32 + q * 8);
        const long long gbase = (long long)blockIdx.x * 256 + w * 64;
        #pragma unroll
        for (int n = 0; n < 4; ++n) {
            f32x4 d = { 0.f, 0.f, 0.f, 0.f };
            d = __builtin_amdgcn_mfma_f32_16x16x32_bf16(af0, *(const bf16x8*)&xb[w][n * 2 + 0][l][0], d, 0, 0, 0);
            d = __builtin_amdgcn_mfma_f32_16x16x32_bf16(af1, *(const bf16x8*)&xb[w][n * 2 + 1][l][0], d, 0, 0, 0);
            if (q < 2) {   // valid output rows p = q*4 + r < 8
                f32x4 o;
                #pragma unroll
                for (int r = 0; r < 4; ++r) {
                    float v = d[r] + bb[128 + q * 4 + r];
                    o[r] = 1.f / (1.f + __expf(-v));
                }
                *(f32x4*)&out[(gbase + n * 16 + l16) * 8 + q * 4] = o;
            }
        }
    }
}

extern "C" void kernel_launch(void* const* d_in, const int* in_sizes, int n_in,
                              void* d_out, int out_size, void* d_ws, size_t ws_size,
                              hipStream_t stream) {
    const float*  ipos   = (const float*)d_in[0];
    const float4* tables = (const float4*)d_in[1];
    const float*  W1 = (const float*)d_in[2];
    const float*  b1 = (const float*)d_in[3];
    const float*  W2 = (const float*)d_in[4];
    const float*  b2 = (const float*)d_in[5];
    const float*  W3 = (const float*)d_in[6];
    const float*  b3 = (const float*)d_in[7];
    float* out = (float*)d_out;

    ResArgs ra;
    const double g = exp((log(512.0) - log(16.0)) / 15.0);   // matches Python libm
    for (int lvl = 0; lvl < 16; ++lvl)
        ra.r[lvl] = (float)floor(16.0 * pow(g, (double)lvl));

    const int n = in_sizes[0] / 3;           // 1<<20
    hashgrid_mlp<<<dim3(n / 256), dim3(256), 0, stream>>>(
        ipos, tables, W1, b1, W2, b2, W3, b3, out, ra);
}

// Round 3
// 712.441 us; speedup vs baseline: 1.1919x; 1.1919x over previous
//
#include <hip/hip_runtime.h>
#include <cmath>

typedef __attribute__((ext_vector_type(8))) short bf16x8;
typedef __attribute__((ext_vector_type(4))) float f32x4;

#define TBLSZ (1 << 18)
#define TMASK (TBLSZ - 1)
#define N_ENTRIES ((long long)16 * TBLSZ)
// ws layout: [tbl_bf: 4M entries x 8B][w1b: 4096 bf16][w2b: 4096][w3b(pad16): 1024]
#define WS_TBL_BYTES (N_ENTRIES * 8)
#define WS_NEED (WS_TBL_BYTES + (4096 + 4096 + 1024) * 2)

struct ResArgs { float r[16]; };

__device__ __forceinline__ unsigned short f2bf(float f) {
    unsigned u = __float_as_uint(f);
    u += 0x7fffu + ((u >> 16) & 1u);   // RTNE
    return (unsigned short)(u >> 16);
}

__global__ __launch_bounds__(256) void conv_tables(
    const float4* __restrict__ tables,
    const float* __restrict__ W1, const float* __restrict__ W2,
    const float* __restrict__ W3,
    uint2* __restrict__ tbl, unsigned short* __restrict__ wbf)
{
    const int t = threadIdx.x;
    for (long long i = (long long)blockIdx.x * 256 + t; i < N_ENTRIES;
         i += (long long)gridDim.x * 256) {
        float4 v = tables[i];
        uint2 p;
        p.x = (unsigned)f2bf(v.x) | ((unsigned)f2bf(v.y) << 16);
        p.y = (unsigned)f2bf(v.z) | ((unsigned)f2bf(v.w) << 16);
        tbl[i] = p;
    }
    if (blockIdx.x == 0) {
        const int base = t * 16;
        #pragma unroll
        for (int e = 0; e < 16; ++e) wbf[base + e] = f2bf(W1[base + e]);
        #pragma unroll
        for (int e = 0; e < 16; ++e) wbf[4096 + base + e] = f2bf(W2[base + e]);
        if (t < 32) {
            #pragma unroll
            for (int e = 0; e < 16; ++e) wbf[8192 + base + e] = f2bf(W3[base + e]);
        } else if (t < 64) {
            #pragma unroll
            for (int e = 0; e < 16; ++e) wbf[8192 + base + e] = 0;
        }
    }
}

__device__ __forceinline__ bf16x8 wfrag_f32(const float* __restrict__ W, int row, int k0) {
    float4 a = *(const float4*)(W + row * 64 + k0);
    float4 b = *(const float4*)(W + row * 64 + k0 + 4);
    bf16x8 r;
    r[0] = f2bf(a.x); r[1] = f2bf(a.y); r[2] = f2bf(a.z); r[3] = f2bf(a.w);
    r[4] = f2bf(b.x); r[5] = f2bf(b.y); r[6] = f2bf(b.z); r[7] = f2bf(b.w);
    return r;
}

template<bool BF>
__global__ __launch_bounds__(256, 4) void hashgrid_mlp(
    const float* __restrict__ ipos,
    const float4* __restrict__ tables_f32,
    const uint2* __restrict__ tbl_bf,
    const unsigned short* __restrict__ wbf,
    const float* __restrict__ W1, const float* __restrict__ W2,
    const float* __restrict__ W3,
    const float* __restrict__ b1, const float* __restrict__ b2,
    const float* __restrict__ b3,
    float* __restrict__ out, ResArgs ra)
{
    // activation blocks in MFMA B-frag layout (per wave):
    // X[i][k] at blk=(iloc>>4)*2+(k>>5), lane=(iloc&15)+16*((k&31)>>3), elem=k&7
    __shared__ __attribute__((aligned(16))) unsigned short xb[4][8][64][8];

    const int t   = threadIdx.x;
    const int w   = t >> 6;
    const int l   = t & 63;
    const int q   = l >> 4;
    const int l16 = l & 15;

    // ---- phase 1: hash-grid encode (one point per thread) ----
    {
        const long long gi = (long long)blockIdx.x * 256 + t;
        const float px = ipos[gi * 3 + 0];
        const float py = ipos[gi * 3 + 1];
        const float pz = ipos[gi * 3 + 2];
        const int n2base = (l >> 4) * 2;

        #pragma unroll 2
        for (int lvl = 0; lvl < 16; ++lvl) {
            const float res = ra.r[lvl];
            float xl = px * res, yl = py * res, zl = pz * res;
            float fx = floorf(xl), fy = floorf(yl), fz = floorf(zl);
            float tx = xl - fx, ty = yl - fy, tz = zl - fz;
            unsigned cx = (unsigned)(int)fx, cy = (unsigned)(int)fy, cz = (unsigned)(int)fz;
            unsigned hx[2] = { cx, cx + 1u };
            unsigned hy[2] = { cy * 2654435761u, cy * 2654435761u + 2654435761u };
            unsigned hz[2] = { cz * 805459861u,  cz * 805459861u + 805459861u };
            float wx[2] = { 1.f - tx, tx }, wy[2] = { 1.f - ty, ty }, wz[2] = { 1.f - tz, tz };
            float a0 = 0.f, a1 = 0.f, a2 = 0.f, a3 = 0.f;
            if constexpr (BF) {
                const uint2* tbl = tbl_bf + (size_t)lvl * TBLSZ;
                #pragma unroll
                for (int c = 0; c < 8; ++c) {
                    const int ox = (c >> 2) & 1, oy = (c >> 1) & 1, oz = c & 1;
                    unsigned h = (hx[ox] ^ hy[oy] ^ hz[oz]) & TMASK;
                    uint2 v = tbl[h];
                    float ww = wx[ox] * wy[oy] * wz[oz];
                    a0 = fmaf(ww, __uint_as_float(v.x << 16), a0);
                    a1 = fmaf(ww, __uint_as_float(v.x & 0xffff0000u), a1);
                    a2 = fmaf(ww, __uint_as_float(v.y << 16), a2);
                    a3 = fmaf(ww, __uint_as_float(v.y & 0xffff0000u), a3);
                }
            } else {
                const float4* tbl = tables_f32 + (size_t)lvl * TBLSZ;
                #pragma unroll
                for (int c = 0; c < 8; ++c) {
                    const int ox = (c >> 2) & 1, oy = (c >> 1) & 1, oz = c & 1;
                    unsigned h = (hx[ox] ^ hy[oy] ^ hz[oz]) & TMASK;
                    float4 v = tbl[h];
                    float ww = wx[ox] * wy[oy] * wz[oz];
                    a0 = fmaf(ww, v.x, a0); a1 = fmaf(ww, v.y, a1);
                    a2 = fmaf(ww, v.z, a2); a3 = fmaf(ww, v.w, a3);
                }
            }
            const int blk = n2base + (lvl >> 3);
            const int lp  = l16 + 16 * ((lvl & 7) >> 1);
            uint2 pk;
            pk.x = (unsigned)f2bf(a0) | ((unsigned)f2bf(a1) << 16);
            pk.y = (unsigned)f2bf(a2) | ((unsigned)f2bf(a3) << 16);
            *(uint2*)&xb[w][blk][lp][(lvl & 1) * 4] = pk;
        }
    }
    // no barrier: each wave reads only its own xb[w] blocks (DS in-order per wave)

    // ---- phase 2: MLP via MFMA, transposed (D = W * X^T) ----
    #pragma unroll 1
    for (int layer = 0; layer < 2; ++layer) {
        const float* bptr = layer ? b2 : b1;
        f32x4 acc[4][4];
        #pragma unroll
        for (int m = 0; m < 4; ++m) {
            bf16x8 af0, af1;
            if constexpr (BF) {
                const unsigned short* wp = wbf + layer * 4096;
                af0 = *(const bf16x8*)(wp + (m * 16 + l16) * 64 +  0 + q * 8);
                af1 = *(const bf16x8*)(wp + (m * 16 + l16) * 64 + 32 + q * 8);
            } else {
                const float* Wp = layer ? W2 : W1;
                af0 = wfrag_f32(Wp, m * 16 + l16,  0 + q * 8);
                af1 = wfrag_f32(Wp, m * 16 + l16, 32 + q * 8);
            }
            #pragma unroll
            for (int n = 0; n < 4; ++n) {
                f32x4 d = { 0.f, 0.f, 0.f, 0.f };
                d = __builtin_amdgcn_mfma_f32_16x16x32_bf16(af0, *(const bf16x8*)&xb[w][n * 2 + 0][l][0], d, 0, 0, 0);
                d = __builtin_amdgcn_mfma_f32_16x16x32_bf16(af1, *(const bf16x8*)&xb[w][n * 2 + 1][l][0], d, 0, 0, 0);
                acc[m][n] = d;
            }
        }
        // bias + relu, deposit h back into xb as next layer's B-frags
        #pragma unroll
        for (int m = 0; m < 4; ++m) {
            #pragma unroll
            for (int n = 0; n < 4; ++n) {
                #pragma unroll
                for (int rr = 0; rr < 4; rr += 2) {
                    const int j0 = m * 16 + q * 4 + rr;
                    float v0 = fmaxf(acc[m][n][rr]     + bptr[j0],     0.f);
                    float v1 = fmaxf(acc[m][n][rr + 1] + bptr[j0 + 1], 0.f);
                    unsigned pk = (unsigned)f2bf(v0) | ((unsigned)f2bf(v1) << 16);
                    const int blk = n * 2 + (j0 >> 5);
                    const int lp  = l16 + 16 * ((j0 & 31) >> 3);
                    *(unsigned*)&xb[w][blk][lp][j0 & 7] = pk;
                }
            }
        }
    }

    // ---- layer 3: [8x64] (padded to 16) + bias + sigmoid, coalesced store ----
    {
        bf16x8 af0, af1;
        if constexpr (BF) {
            af0 = *(const bf16x8*)(wbf + 8192 + l16 * 64 +  0 + q * 8);
            af1 = *(const bf16x8*)(wbf + 8192 + l16 * 64 + 32 + q * 8);
        } else {
            if (l16 < 8) {
                af0 = wfrag_f32(W3, l16,  0 + q * 8);
                af1 = wfrag_f32(W3, l16, 32 + q * 8);
            } else {
                af0 = bf16x8{0,0,0,0,0,0,0,0};
                af1 = bf16x8{0,0,0,0,0,0,0,0};
            }
        }
        const long long gbase = (long long)blockIdx.x * 256 + w * 64;
        #pragma unroll
        for (int n = 0; n < 4; ++n) {
            f32x4 d = { 0.f, 0.f, 0.f, 0.f };
            d = __builtin_amdgcn_mfma_f32_16x16x32_bf16(af0, *(const bf16x8*)&xb[w][n * 2 + 0][l][0], d, 0, 0, 0);
            d = __builtin_amdgcn_mfma_f32_16x16x32_bf16(af1, *(const bf16x8*)&xb[w][n * 2 + 1][l][0], d, 0, 0, 0);
            if (q < 2) {   // valid output rows p = q*4 + r < 8
                f32x4 o;
                #pragma unroll
                for (int r = 0; r < 4; ++r) {
                    float v = d[r] + b3[q * 4 + r];
                    o[r] = 1.f / (1.f + __expf(-v));
                }
                *(f32x4*)&out[(gbase + n * 16 + l16) * 8 + q * 4] = o;
            }
        }
    }
}

extern "C" void kernel_launch(void* const* d_in, const int* in_sizes, int n_in,
                              void* d_out, int out_size, void* d_ws, size_t ws_size,
                              hipStream_t stream) {
    const float*  ipos   = (const float*)d_in[0];
    const float4* tables = (const float4*)d_in[1];
    const float*  W1 = (const float*)d_in[2];
    const float*  b1 = (const float*)d_in[3];
    const float*  W2 = (const float*)d_in[4];
    const float*  b2 = (const float*)d_in[5];
    const float*  W3 = (const float*)d_in[6];
    const float*  b3 = (const float*)d_in[7];
    float* out = (float*)d_out;

    ResArgs ra;
    const double g = exp((log(512.0) - log(16.0)) / 15.0);   // matches Python libm
    for (int lvl = 0; lvl < 16; ++lvl)
        ra.r[lvl] = (float)floor(16.0 * pow(g, (double)lvl));

    const int n = in_sizes[0] / 3;           // 1<<20

    uint2* tbl_bf = (uint2*)d_ws;
    unsigned short* wbf = (unsigned short*)((char*)d_ws + WS_TBL_BYTES);

    if (ws_size >= (size_t)WS_NEED) {        // ws_size constant per harness -> deterministic
        conv_tables<<<dim3(2048), dim3(256), 0, stream>>>(tables, W1, W2, W3, tbl_bf, wbf);
        hashgrid_mlp<true><<<dim3(n / 256), dim3(256), 0, stream>>>(
            ipos, tables, tbl_bf, wbf, W1, W2, W3, b1, b2, b3, out, ra);
    } else {
        hashgrid_mlp<false><<<dim3(n / 256), dim3(256), 0, stream>>>(
            ipos, tables, tbl_bf, wbf, W1, W2, W3, b1, b2, b3, out, ra);
    }
}